// Round 1
// baseline (3878.499 us; speedup 1.0000x reference)
//
#include <hip/hip_runtime.h>
#include <hip/hip_bf16.h>
#include <cstddef>

#define NB 2048
#define TENC 168
#define TPRED 24

// ---------------------------------------------------------------------------
// Phase 1: recurrent dilated-conv decoder. One wave (64 lanes) per batch
// element; 8 elements per 512-thread block; 256 blocks total.
// All small weights live in LDS. Dilation rings hold only the live history:
// sizes {1,2,4,8,8} for d={1,2,4,8,16}; d=32 always reads the encoder tail.
// Writes post-relu skips (row = e*24+t, col = l*64+k) for phase 2.
// ---------------------------------------------------------------------------
__global__ __launch_bounds__(512, 1) void dec_phase1(
    const float* __restrict__ feat,    // [2048][24][15]
    const float* __restrict__ dinit,   // [2048][1]
    const float* __restrict__ enc,     // [6][2048][168][64]
    const float* __restrict__ W1,      // [16][64]
    const float* __restrict__ b1,      // [64]
    const float* __restrict__ W2,      // [64][128]
    const float* __restrict__ b2,      // [128]
    const float* __restrict__ W3,      // [64][128]
    const float* __restrict__ W4,      // [64][128]
    const float* __restrict__ b4,      // [128]
    float* __restrict__ skbuf)         // [2048*24][384]
{
  // W23p[i][p] = { W23[i][p], W23[i][p+64] }, rows 0..63 = W2, 64..127 = W3.
  __shared__ float2 W23p[128 * 64];    // 64 KB
  __shared__ float2 W4p[64 * 64];      // 32 KB
  __shared__ float  W1s[16 * 64];      // 4 KB
  __shared__ float  b2s[128], b4s[128], b1s[64];
  __shared__ float  ring[8][23 * 64];  // 46 KB  (per-element dilation rings)
  __shared__ float  sx[8][128];        // [state | x] per element
  __shared__ float  gt[8][64];         // gated per element

  const int tid = threadIdx.x;

  for (int k = tid; k < 128 * 64; k += 512) {
    const int i = k >> 6, p = k & 63;
    const float* src = (i < 64) ? (W2 + i * 128) : (W3 + (i - 64) * 128);
    W23p[k] = make_float2(src[p], src[p + 64]);
  }
  for (int k = tid; k < 64 * 64; k += 512) {
    const int i = k >> 6, p = k & 63;
    W4p[k] = make_float2(W4[i * 128 + p], W4[i * 128 + p + 64]);
  }
  for (int k = tid; k < 16 * 64; k += 512) W1s[k] = W1[k];
  if (tid < 128) { b2s[tid] = b2[tid]; b4s[tid] = b4[tid]; }
  else if (tid < 192) b1s[tid - 128] = b1[tid - 128];
  __syncthreads();

  const int wid  = tid >> 6;
  const int lane = tid & 63;
  const int e    = blockIdx.x * 8 + wid;
  const float ini = dinit[e];

  for (int t = 0; t < TPRED; ++t) {
    // ---- input embedding: x = tanh([init, feat_t] @ W1 + b1) ----
    float u = b1s[lane] + ini * W1s[lane];
    const float* fp = feat + ((size_t)e * TPRED + t) * 15;
    #pragma unroll
    for (int i = 0; i < 15; ++i) u += fp[i] * W1s[(i + 1) * 64 + lane];
    float x = tanhf(u);
    sx[wid][64 + lane] = x;

    #pragma unroll
    for (int l = 0; l < 6; ++l) {
      const int d    = 1 << l;
      const int roff = (l == 0) ? 0 : (l == 1) ? 1 : (l == 2) ? 3 : (l == 3) ? 7 : 15;
      const int rsz  = (l >= 4) ? 8 : d;   // l==5 never uses the ring

      // ---- state ----
      float st;
      if (t < d) {
        st = enc[(((size_t)l * NB + e) * TENC + (TENC + t - d)) * 64 + lane];
      } else {
        st = ring[wid][(roff + (t % rsz)) * 64 + lane];
      }
      sx[wid][lane] = st;
      __syncthreads();

      // ---- dc = [state|x] @ [W2;W3] + b2 ; lane owns cols (lane, lane+64) ----
      float a = b2s[lane], b = b2s[64 + lane];
      #pragma unroll
      for (int i = 0; i < 128; i += 4) {
        const float4 s4 = *(const float4*)&sx[wid][i];
        float2 w;
        w = W23p[(i + 0) * 64 + lane]; a += s4.x * w.x; b += s4.x * w.y;
        w = W23p[(i + 1) * 64 + lane]; a += s4.y * w.x; b += s4.y * w.y;
        w = W23p[(i + 2) * 64 + lane]; a += s4.z * w.x; b += s4.z * w.y;
        w = W23p[(i + 3) * 64 + lane]; a += s4.w * w.x; b += s4.w * w.y;
      }
      const float gg = tanhf(a) * (1.0f / (1.0f + __expf(-b)));
      gt[wid][lane] = gg;
      __syncthreads();

      // ---- out = gated @ W4 + b4 ; skip = out[:64], res = out[64:] ----
      float sk = b4s[lane], rs = b4s[64 + lane];
      #pragma unroll
      for (int i = 0; i < 64; i += 4) {
        const float4 g4 = *(const float4*)&gt[wid][i];
        float2 w;
        w = W4p[(i + 0) * 64 + lane]; sk += g4.x * w.x; rs += g4.x * w.y;
        w = W4p[(i + 1) * 64 + lane]; sk += g4.y * w.x; rs += g4.y * w.y;
        w = W4p[(i + 2) * 64 + lane]; sk += g4.z * w.x; rs += g4.z * w.y;
        w = W4p[(i + 3) * 64 + lane]; sk += g4.w * w.x; rs += g4.w * w.y;
      }
      const float xn = sx[wid][64 + lane] + rs;
      skbuf[(((size_t)e * TPRED + t) * 6 + l) * 64 + lane] = fmaxf(sk, 0.0f);
      // lane-private updates; cross-lane reads happen only after the next
      // __syncthreads() inside the following layer iteration.
      sx[wid][64 + lane] = xn;
      if (l < 5 && t + d <= 23) ring[wid][(roff + (t % rsz)) * 64 + lane] = xn;
    }
  }
}

// ---------------------------------------------------------------------------
// Phase 2: y = relu( relu(sk) @ W5 + b5 ) @ W6 + b6  for 49152 rows.
// Classic 128x128-tile register-blocked fp32 GEMM (K=384), fused head.
// ---------------------------------------------------------------------------
__global__ __launch_bounds__(256, 2) void dec_phase2(
    const float* __restrict__ skbuf,   // [49152][384], already relu'd
    const float* __restrict__ W5,      // [384][128]
    const float* __restrict__ b5,      // [128]
    const float* __restrict__ W6,      // [128]
    const float* __restrict__ b6,      // [1]
    float* __restrict__ out)           // [49152]
{
  __shared__ float As[16][128];        // A^T tile: As[k][row]
  __shared__ float Bs[16][128];        // W5 tile:  Bs[k][col]
  __shared__ float red[128][17];

  const int tid = threadIdx.x;
  const int R0  = blockIdx.x * 128;
  const int tr  = tid >> 4;            // 16 row-groups of 8 rows
  const int tc  = tid & 15;            // 16 col-groups of 8 cols

  float acc[8][8];
  #pragma unroll
  for (int r = 0; r < 8; ++r)
    #pragma unroll
    for (int c = 0; c < 8; ++c) acc[r][c] = 0.0f;

  for (int kb = 0; kb < 384; kb += 16) {
    #pragma unroll
    for (int q = tid; q < 512; q += 256) {
      const int row = q >> 2, kc = (q & 3) * 4;
      const float4 v = *(const float4*)&skbuf[(size_t)(R0 + row) * 384 + kb + kc];
      As[kc + 0][row] = v.x; As[kc + 1][row] = v.y;
      As[kc + 2][row] = v.z; As[kc + 3][row] = v.w;
    }
    #pragma unroll
    for (int q = tid; q < 512; q += 256) {
      const int k = q >> 5, c4 = (q & 31) * 4;
      *(float4*)&Bs[k][c4] = *(const float4*)&W5[(size_t)(kb + k) * 128 + c4];
    }
    __syncthreads();

    #pragma unroll
    for (int k = 0; k < 16; ++k) {
      float av[8], bv[8];
      *(float4*)&av[0] = *(const float4*)&As[k][tr * 8];
      *(float4*)&av[4] = *(const float4*)&As[k][tr * 8 + 4];
      *(float4*)&bv[0] = *(const float4*)&Bs[k][tc * 8];
      *(float4*)&bv[4] = *(const float4*)&Bs[k][tc * 8 + 4];
      #pragma unroll
      for (int r = 0; r < 8; ++r)
        #pragma unroll
        for (int c = 0; c < 8; ++c) acc[r][c] += av[r] * bv[c];
    }
    __syncthreads();
  }

  // fused head: h = relu(acc + b5), partial y = h @ W6
  float py[8];
  #pragma unroll
  for (int r = 0; r < 8; ++r) py[r] = 0.0f;
  #pragma unroll
  for (int c = 0; c < 8; ++c) {
    const float w6 = W6[tc * 8 + c];
    const float bb = b5[tc * 8 + c];
    #pragma unroll
    for (int r = 0; r < 8; ++r) py[r] += fmaxf(acc[r][c] + bb, 0.0f) * w6;
  }
  #pragma unroll
  for (int r = 0; r < 8; ++r) red[tr * 8 + r][tc] = py[r];
  __syncthreads();

  if (tid < 128) {
    float y = b6[0];
    #pragma unroll
    for (int c = 0; c < 16; ++c) y += red[tid][c];
    out[R0 + tid] = y;
  }
}

extern "C" void kernel_launch(void* const* d_in, const int* in_sizes, int n_in,
                              void* d_out, int out_size, void* d_ws, size_t ws_size,
                              hipStream_t stream) {
  const float* feat  = (const float*)d_in[0];
  const float* dinit = (const float*)d_in[1];
  const float* enc   = (const float*)d_in[2];
  const float* W1    = (const float*)d_in[3];
  const float* b1    = (const float*)d_in[4];
  const float* W2    = (const float*)d_in[5];
  const float* b2    = (const float*)d_in[6];
  const float* W3    = (const float*)d_in[7];
  const float* W4    = (const float*)d_in[8];
  const float* b4    = (const float*)d_in[9];
  const float* W5    = (const float*)d_in[10];
  const float* b5    = (const float*)d_in[11];
  const float* W6    = (const float*)d_in[12];
  const float* b6    = (const float*)d_in[13];

  float* out   = (float*)d_out;
  float* skbuf = (float*)d_ws;   // needs 49152*384*4 = 75.5 MB of workspace

  dec_phase1<<<dim3(256), dim3(512), 0, stream>>>(
      feat, dinit, enc, W1, b1, W2, b2, W3, W4, b4, skbuf);
  dec_phase2<<<dim3(384), dim3(256), 0, stream>>>(
      skbuf, W5, b5, W6, b6, out);
}

// Round 2
// 3612.543 us; speedup vs baseline: 1.0736x; 1.0736x over previous
//
#include <hip/hip_runtime.h>
#include <hip/hip_bf16.h>
#include <cstddef>

#define NB 2048
#define TENC 168
#define TPRED 24

// ---------------------------------------------------------------------------
// Phase 1: recurrent dilated-conv decoder. One wave (64 lanes) per batch
// element; 8 elements per 512-thread block; 256 blocks total.
// All small weights live in LDS. Dilation rings hold only the live history:
// sizes {1,2,4,8,8} for d={1,2,4,8,16}; d=32 always reads the encoder tail.
//
// Round 2: t/l loops kept ROLLED (round-1 full unroll produced ~1MB of code ->
// L1I thrash, IPC 0.03). No __syncthreads in the steady state: all LDS state
// (sx/gt/ring) is private to each wave's wid slice; cross-lane visibility
// within a wave needs only lgkmcnt(0).
// ---------------------------------------------------------------------------
__global__ __launch_bounds__(512, 1) void dec_phase1(
    const float* __restrict__ feat,    // [2048][24][15]
    const float* __restrict__ dinit,   // [2048][1]
    const float* __restrict__ enc,     // [6][2048][168][64]
    const float* __restrict__ W1,      // [16][64]
    const float* __restrict__ b1,      // [64]
    const float* __restrict__ W2,      // [64][128]
    const float* __restrict__ b2,      // [128]
    const float* __restrict__ W3,      // [64][128]
    const float* __restrict__ W4,      // [64][128]
    const float* __restrict__ b4,      // [128]
    float* __restrict__ skbuf)         // [2048*24][6*64]
{
  // W23p[i*64+p] = { W23[i][p], W23[i][p+64] }, rows 0..63 = W2, 64..127 = W3.
  __shared__ float2 W23p[128 * 64];    // 64 KB
  __shared__ float2 W4p[64 * 64];      // 32 KB
  __shared__ float  W1s[16 * 64];      // 4 KB
  __shared__ float  b2s[128], b4s[128], b1s[64];
  __shared__ float  ring[8][23 * 64];  // 46 KB  (per-element dilation rings)
  __shared__ float  sx[8][128];        // [state | x] per element
  __shared__ float  gt[8][64];         // gated per element

  const int tid = threadIdx.x;

  for (int k = tid; k < 128 * 64; k += 512) {
    const int i = k >> 6, p = k & 63;
    const float* src = (i < 64) ? (W2 + i * 128) : (W3 + (i - 64) * 128);
    W23p[k] = make_float2(src[p], src[p + 64]);
  }
  for (int k = tid; k < 64 * 64; k += 512) {
    const int i = k >> 6, p = k & 63;
    W4p[k] = make_float2(W4[i * 128 + p], W4[i * 128 + p + 64]);
  }
  for (int k = tid; k < 16 * 64; k += 512) W1s[k] = W1[k];
  if (tid < 128) { b2s[tid] = b2[tid]; b4s[tid] = b4[tid]; }
  else if (tid < 192) b1s[tid - 128] = b1[tid - 128];
  __syncthreads();   // the only block-wide barrier

  const int wid  = tid >> 6;
  const int lane = tid & 63;
  const int e    = blockIdx.x * 8 + wid;
  const float ini = dinit[e];

#pragma clang loop unroll(disable)
  for (int t = 0; t < TPRED; ++t) {
    // ---- input embedding: x = tanh([init, feat_t] @ W1 + b1) ----
    float u = b1s[lane] + ini * W1s[lane];
    const float* fp = feat + ((size_t)e * TPRED + t) * 15;
    #pragma unroll
    for (int i = 0; i < 15; ++i) u += fp[i] * W1s[(i + 1) * 64 + lane];
    float x = tanhf(u);
    sx[wid][64 + lane] = x;

#pragma clang loop unroll(disable)
    for (int l = 0; l < 6; ++l) {
      const int d    = 1 << l;
      const int roff = d - 1;           // ring base: l=0..4 -> 0,1,3,7,15
      const int msk  = (d - 1) & 7;     // ring slot mask (sizes 1,2,4,8,8)

      // ---- state ----
      float st;
      if (t < d) {
        st = enc[(((size_t)l * NB + e) * TENC + (TENC + t - d)) * 64 + lane];
      } else {
        st = ring[wid][(roff + (t & msk)) * 64 + lane];
      }
      sx[wid][lane] = st;
      asm volatile("s_waitcnt lgkmcnt(0)" ::: "memory");

      // ---- dc = [state|x] @ [W2;W3] + b2 ; lane owns cols (lane, lane+64) ----
      float a = b2s[lane], b = b2s[64 + lane];
      #pragma unroll
      for (int i = 0; i < 128; i += 4) {
        const float4 s4 = *(const float4*)&sx[wid][i];
        float2 w;
        w = W23p[(i + 0) * 64 + lane]; a += s4.x * w.x; b += s4.x * w.y;
        w = W23p[(i + 1) * 64 + lane]; a += s4.y * w.x; b += s4.y * w.y;
        w = W23p[(i + 2) * 64 + lane]; a += s4.z * w.x; b += s4.z * w.y;
        w = W23p[(i + 3) * 64 + lane]; a += s4.w * w.x; b += s4.w * w.y;
      }
      const float gg = tanhf(a) * (1.0f / (1.0f + __expf(-b)));
      gt[wid][lane] = gg;
      asm volatile("s_waitcnt lgkmcnt(0)" ::: "memory");

      // ---- out = gated @ W4 + b4 ; skip = out[:64], res = out[64:] ----
      float sk = b4s[lane], rs = b4s[64 + lane];
      #pragma unroll
      for (int i = 0; i < 64; i += 4) {
        const float4 g4 = *(const float4*)&gt[wid][i];
        float2 w;
        w = W4p[(i + 0) * 64 + lane]; sk += g4.x * w.x; rs += g4.x * w.y;
        w = W4p[(i + 1) * 64 + lane]; sk += g4.y * w.x; rs += g4.y * w.y;
        w = W4p[(i + 2) * 64 + lane]; sk += g4.z * w.x; rs += g4.z * w.y;
        w = W4p[(i + 3) * 64 + lane]; sk += g4.w * w.x; rs += g4.w * w.y;
      }
      const float xn = sx[wid][64 + lane] + rs;
      skbuf[(((size_t)e * TPRED + t) * 6 + l) * 64 + lane] = fmaxf(sk, 0.0f);
      // lane-private updates; made visible by the lgkmcnt(0) fence at the
      // top of the next layer/step before any cross-lane read.
      sx[wid][64 + lane] = xn;
      if (l < 5 && t + d <= 23) ring[wid][(roff + (t & msk)) * 64 + lane] = xn;
    }
  }
}

// ---------------------------------------------------------------------------
// Phase 2: y = relu( relu(sk) @ W5 + b5 ) @ W6 + b6  for 49152 rows.
// Classic 128x128-tile register-blocked fp32 GEMM (K=384), fused head.
// ---------------------------------------------------------------------------
__global__ __launch_bounds__(256, 2) void dec_phase2(
    const float* __restrict__ skbuf,   // [49152][384], already relu'd
    const float* __restrict__ W5,      // [384][128]
    const float* __restrict__ b5,      // [128]
    const float* __restrict__ W6,      // [128]
    const float* __restrict__ b6,      // [1]
    float* __restrict__ out)           // [49152]
{
  __shared__ float As[16][128];        // A^T tile: As[k][row]
  __shared__ float Bs[16][128];        // W5 tile:  Bs[k][col]
  __shared__ float red[128][17];

  const int tid = threadIdx.x;
  const int R0  = blockIdx.x * 128;
  const int tr  = tid >> 4;            // 16 row-groups of 8 rows
  const int tc  = tid & 15;            // 16 col-groups of 8 cols

  float acc[8][8];
  #pragma unroll
  for (int r = 0; r < 8; ++r)
    #pragma unroll
    for (int c = 0; c < 8; ++c) acc[r][c] = 0.0f;

  for (int kb = 0; kb < 384; kb += 16) {
    #pragma unroll
    for (int q = tid; q < 512; q += 256) {
      const int row = q >> 2, kc = (q & 3) * 4;
      const float4 v = *(const float4*)&skbuf[(size_t)(R0 + row) * 384 + kb + kc];
      As[kc + 0][row] = v.x; As[kc + 1][row] = v.y;
      As[kc + 2][row] = v.z; As[kc + 3][row] = v.w;
    }
    #pragma unroll
    for (int q = tid; q < 512; q += 256) {
      const int k = q >> 5, c4 = (q & 31) * 4;
      *(float4*)&Bs[k][c4] = *(const float4*)&W5[(size_t)(kb + k) * 128 + c4];
    }
    __syncthreads();

    #pragma unroll
    for (int k = 0; k < 16; ++k) {
      float av[8], bv[8];
      *(float4*)&av[0] = *(const float4*)&As[k][tr * 8];
      *(float4*)&av[4] = *(const float4*)&As[k][tr * 8 + 4];
      *(float4*)&bv[0] = *(const float4*)&Bs[k][tc * 8];
      *(float4*)&bv[4] = *(const float4*)&Bs[k][tc * 8 + 4];
      #pragma unroll
      for (int r = 0; r < 8; ++r)
        #pragma unroll
        for (int c = 0; c < 8; ++c) acc[r][c] += av[r] * bv[c];
    }
    __syncthreads();
  }

  // fused head: h = relu(acc + b5), partial y = h @ W6
  float py[8];
  #pragma unroll
  for (int r = 0; r < 8; ++r) py[r] = 0.0f;
  #pragma unroll
  for (int c = 0; c < 8; ++c) {
    const float w6 = W6[tc * 8 + c];
    const float bb = b5[tc * 8 + c];
    #pragma unroll
    for (int r = 0; r < 8; ++r) py[r] += fmaxf(acc[r][c] + bb, 0.0f) * w6;
  }
  #pragma unroll
  for (int r = 0; r < 8; ++r) red[tr * 8 + r][tc] = py[r];
  __syncthreads();

  if (tid < 128) {
    float y = b6[0];
    #pragma unroll
    for (int c = 0; c < 16; ++c) y += red[tid][c];
    out[R0 + tid] = y;
  }
}

extern "C" void kernel_launch(void* const* d_in, const int* in_sizes, int n_in,
                              void* d_out, int out_size, void* d_ws, size_t ws_size,
                              hipStream_t stream) {
  const float* feat  = (const float*)d_in[0];
  const float* dinit = (const float*)d_in[1];
  const float* enc   = (const float*)d_in[2];
  const float* W1    = (const float*)d_in[3];
  const float* b1    = (const float*)d_in[4];
  const float* W2    = (const float*)d_in[5];
  const float* b2    = (const float*)d_in[6];
  const float* W3    = (const float*)d_in[7];
  const float* W4    = (const float*)d_in[8];
  const float* b4    = (const float*)d_in[9];
  const float* W5    = (const float*)d_in[10];
  const float* b5    = (const float*)d_in[11];
  const float* W6    = (const float*)d_in[12];
  const float* b6    = (const float*)d_in[13];

  float* out   = (float*)d_out;
  float* skbuf = (float*)d_ws;   // needs 49152*384*4 = 75.5 MB of workspace

  dec_phase1<<<dim3(256), dim3(512), 0, stream>>>(
      feat, dinit, enc, W1, b1, W2, b2, W3, W4, b4, skbuf);
  dec_phase2<<<dim3(384), dim3(256), 0, stream>>>(
      skbuf, W5, b5, W6, b6, out);
}